// Round 2
// baseline (1303.975 us; speedup 1.0000x reference)
//
#include <hip/hip_runtime.h>
#include <hip/hip_bf16.h>

// Problem constants (from reference): B=4, S=64, F=64, V=16384, E=512
#define BB 4
#define SS 64
#define FF 64
#define VV 16384
#define EE 512

// ---------------------------------------------------------------------------
// Kernel 1: transpose W [E,V] -> Wt [V,E] via LDS tile (coalesced both sides)
// ---------------------------------------------------------------------------
#define TILE 32
__global__ __launch_bounds__(256) void transpose_w(const float* __restrict__ W,
                                                   float* __restrict__ Wt) {
    __shared__ float tile[TILE][TILE + 1];  // +1 pad: avoid 32-way bank conflict
    const int v0 = blockIdx.x * TILE;   // along V (16384/32 = 512 blocks)
    const int e0 = blockIdx.y * TILE;   // along E (512/32   = 16 blocks)
    const int tx = threadIdx.x;         // 0..31
    const int ty = threadIdx.y;         // 0..7

#pragma unroll
    for (int j = 0; j < TILE; j += 8)
        tile[ty + j][tx] = W[(size_t)(e0 + ty + j) * VV + v0 + tx];
    __syncthreads();
#pragma unroll
    for (int j = 0; j < TILE; j += 8)
        Wt[(size_t)(v0 + ty + j) * EE + e0 + tx] = tile[tx][ty + j];
}

// ---------------------------------------------------------------------------
// Kernel 2: one wave (64 lanes) per (b,s,f) row.
//   Phase A: scan x row (16384 fp32) in float4 chunks (256 floats/wave-iter),
//            wave-early-exit on first nonzero (one-hot), shuffle-min broadcast.
//   Phase B: out[row,:] = Wt[idx,:] + pos_emb[s,:] + fmap_emb[f,:]
// 4 waves per 256-thread block -> 4 rows/block, 4096 blocks.
// ---------------------------------------------------------------------------
__global__ __launch_bounds__(256) void combined_embed(
        const float* __restrict__ x,
        const float* __restrict__ W,      // [E,V] (fallback path)
        const float* __restrict__ Wt,     // [V,E] (fast path)
        const float* __restrict__ pos_emb,
        const float* __restrict__ fmap_emb,
        float* __restrict__ out,
        int use_wt) {
    const int lane = threadIdx.x & 63;
    const int wave = threadIdx.x >> 6;
    const int row  = blockIdx.x * 4 + wave;   // 0 .. B*S*F-1 = 16383

    // ---- Phase A: find one-hot index in x[row, :] ----
    const float4* xr = (const float4*)(x + (size_t)row * VV);
    int idx = 0;
#pragma unroll 1
    for (int it = 0; it < VV / (64 * 4); ++it) {   // 64 iterations max, 256 floats each
        float4 v = xr[it * 64 + lane];
        int p = -1;
        if (v.x != 0.0f) p = 0;
        else if (v.y != 0.0f) p = 1;
        else if (v.z != 0.0f) p = 2;
        else if (v.w != 0.0f) p = 3;
        if (__any(p >= 0)) {
            // float index within row = (it*64 + lane)*4 + p = it*256 + lane*4 + p
            int cand = (p >= 0) ? (it * 256 + lane * 4 + p) : 0x7fffffff;
#pragma unroll
            for (int off = 32; off; off >>= 1)
                cand = min(cand, __shfl_xor(cand, off));
            idx = cand;
            break;
        }
    }

    // ---- Phase B: gather + add + store (512 floats, 8 per lane) ----
    const int f = row & (FF - 1);
    const int s = (row >> 6) & (SS - 1);
    const float4* prow = (const float4*)(pos_emb  + (size_t)s * EE);
    const float4* frow = (const float4*)(fmap_emb + (size_t)f * EE);
    float4*       orow = (float4*)(out + (size_t)row * EE);

    if (use_wt) {
        const float4* wrow = (const float4*)(Wt + (size_t)idx * EE);
#pragma unroll
        for (int j = 0; j < 2; ++j) {
            const int e4 = j * 64 + lane;
            float4 w = wrow[e4];
            float4 p = prow[e4];
            float4 fm = frow[e4];
            orow[e4] = make_float4(w.x + p.x + fm.x, w.y + p.y + fm.y,
                                   w.z + p.z + fm.z, w.w + p.w + fm.w);
        }
    } else {
        // Fallback: strided column gather from W [E,V] (L2/L3 absorbs reuse)
#pragma unroll
        for (int j = 0; j < 2; ++j) {
            const int e4 = j * 64 + lane;
            float4 p = prow[e4];
            float4 fm = frow[e4];
            float4 w;
            w.x = W[(size_t)(e4 * 4 + 0) * VV + idx];
            w.y = W[(size_t)(e4 * 4 + 1) * VV + idx];
            w.z = W[(size_t)(e4 * 4 + 2) * VV + idx];
            w.w = W[(size_t)(e4 * 4 + 3) * VV + idx];
            orow[e4] = make_float4(w.x + p.x + fm.x, w.y + p.y + fm.y,
                                   w.z + p.z + fm.z, w.w + p.w + fm.w);
        }
    }
}

extern "C" void kernel_launch(void* const* d_in, const int* in_sizes, int n_in,
                              void* d_out, int out_size, void* d_ws, size_t ws_size,
                              hipStream_t stream) {
    const float* x        = (const float*)d_in[0];  // [B,S,F,V]
    const float* W        = (const float*)d_in[1];  // [E,V]
    const float* pos_emb  = (const float*)d_in[2];  // [256,E]
    const float* fmap_emb = (const float*)d_in[3];  // [256,E]
    float* out = (float*)d_out;                     // [B,S,F,E]

    const size_t wt_bytes = (size_t)VV * EE * sizeof(float);  // 33.55 MB
    const int use_wt = (ws_size >= wt_bytes) ? 1 : 0;
    float* Wt = (float*)d_ws;

    if (use_wt) {
        dim3 grid(VV / TILE, EE / TILE);   // (512, 16)
        dim3 block(32, 8);
        transpose_w<<<grid, block, 0, stream>>>(W, Wt);
    }

    const int rows = BB * SS * FF;         // 16384
    combined_embed<<<rows / 4, 256, 0, stream>>>(x, W, Wt, pos_emb, fmap_emb,
                                                 out, use_wt);
}